// Round 8
// baseline (162.780 us; speedup 1.0000x reference)
//
#include <hip/hip_runtime.h>
#include <hip/hip_bf16.h>
#include <math.h>

typedef unsigned short u16;
typedef unsigned int   u32;
typedef __attribute__((ext_vector_type(8))) short  bf16x8;
typedef __attribute__((ext_vector_type(4))) float  floatx4;

#define NB 2
#define NT 4
#define CK 64
#define CV 256
#define HH 64
#define WW 64
#define MM 4096    // NT*32*32
#define NN 4096    // HH*WW
#define SCALE 0.125f
#define SHIFT 4.0f
#define OUT_B 2097152      // f32 elems per batch in out (512*4096)
#define NW 64              // n-columns per attn block
#define NIT 32             // MM / 128
// exp(x*SCALE - SHIFT) = exp2(x*C1 + C2)
#define C1 0.18033688011112042f
#define C2 (-5.770780163555853f)

__device__ __forceinline__ u16 f2b(float f) {
    __hip_bfloat16 h = __float2bfloat16(f);
    union { __hip_bfloat16 h; u16 u; } v; v.h = h; return v.u;
}

// ============================ fast (MFMA) path ============================
// prep: K -> pk2[b][cblk(8)][m(4096)][8c]  (fragment-tiled, 16B stores)
//       V -> vt[b][c][m]                    (8B ushort4 stores)
//       qv -> out[:, 0:256, :, :]           (float4 copy)
#define PRE_K 65536        // NB*8*4096
#define PRE_V 589824       // + NB*CV*MM/4 (=524288)
#define PRE_T 1114112      // + NB*CV*HH*WW/4 (=524288)

__global__ void prep(const float* __restrict__ mk, const float* __restrict__ mv,
                     const float4* __restrict__ qv,
                     u16* __restrict__ pk2, u16* __restrict__ vt,
                     float* __restrict__ out) {
    int u = blockIdx.x * 256 + threadIdx.x;
    if (u < PRE_K) {
        // one thread = 8 c-values at one m -> coalesced float2 reads, 16B write
        int m = u & 4095, cb8 = (u >> 12) & 7, b = u >> 15;
        int t = m >> 10, hh = (m >> 5) & 31, ww = m & 31;
        const float* s0 = mk + ((size_t)((b*NT + t)*CK + cb8*8))*(HH*WW)
                             + (2*hh)*WW + 2*ww;
        bf16x8 fr;
        #pragma unroll
        for (int i = 0; i < 8; ++i) {
            const float* s = s0 + (size_t)i*(HH*WW);
            float2 r0 = *(const float2*)s;
            float2 r1 = *(const float2*)(s + WW);
            fr[i] = (short)f2b(fmaxf(fmaxf(r0.x, r0.y), fmaxf(r1.x, r1.y)));
        }
        *(bf16x8*)(pk2 + ((size_t)(b*8 + cb8)*MM + m)*8) = fr;
    } else if (u < PRE_V) {
        // one thread = 4 consecutive m at one c -> float4 reads, 8B write
        int u2 = u - PRE_K;
        int m4 = u2 & 1023, c = (u2 >> 10) & 255, b = u2 >> 18;
        int t = m4 >> 8, hh = (m4 >> 3) & 31, w8 = m4 & 7;
        const float* s0 = mv + ((size_t)((b*NT + t)*CV + c))*(HH*WW)
                             + (2*hh)*WW + 8*w8;
        float4 a0 = *(const float4*)(s0);
        float4 a1 = *(const float4*)(s0 + 4);
        float4 b0 = *(const float4*)(s0 + WW);
        float4 b1 = *(const float4*)(s0 + WW + 4);
        ushort4 r;
        r.x = f2b(fmaxf(fmaxf(a0.x, a0.y), fmaxf(b0.x, b0.y)));
        r.y = f2b(fmaxf(fmaxf(a0.z, a0.w), fmaxf(b0.z, b0.w)));
        r.z = f2b(fmaxf(fmaxf(a1.x, a1.y), fmaxf(b1.x, b1.y)));
        r.w = f2b(fmaxf(fmaxf(a1.z, a1.w), fmaxf(b1.z, b1.w)));
        *(ushort4*)(vt + ((size_t)(b*CV + c)*MM) + m4*4) = r;
    } else {
        int u3 = u - PRE_V;
        int b = u3 >> 18, ru = u3 & 262143;
        ((float4*)out)[(size_t)b*(OUT_B/4) + ru] = qv[u3];
    }
}

// ---- attn phases ----
// QK: wave w owns m-rows [16w,16w+16) of the 128-m iter, all 64 n.
// S C-layout: n_l = t*16+lrow, m_l = 16w + quad*4 + r.
__device__ __forceinline__ void qk_phase(bf16x8 k0, bf16x8 k1,
        const bf16x8 (&qf)[2][4], float (&sacc)[4],
        u16* __restrict__ Pd, int lrow, int cbw, int sw)
{
    #pragma unroll
    for (int t = 0; t < 4; ++t) {
        floatx4 s = __builtin_amdgcn_mfma_f32_16x16x32_bf16(
                        k0, qf[0][t], (floatx4){0.f,0.f,0.f,0.f}, 0, 0, 0);
        s = __builtin_amdgcn_mfma_f32_16x16x32_bf16(k1, qf[1][t], s, 0, 0, 0);
        float p0 = exp2f(__builtin_fmaf(s[0], C1, C2));
        float p1 = exp2f(__builtin_fmaf(s[1], C1, C2));
        float p2 = exp2f(__builtin_fmaf(s[2], C1, C2));
        float p3 = exp2f(__builtin_fmaf(s[3], C1, C2));
        sacc[t] += (p0 + p1) + (p2 + p3);
        u32 d0 = (u32)f2b(p0) | ((u32)f2b(p1) << 16);
        u32 d1 = (u32)f2b(p2) | ((u32)f2b(p3) << 16);
        *(uint2*)&Pd[(t*16 + lrow)*128 + ((cbw ^ sw) << 2)] = make_uint2(d0, d1);
    }
}

// PV 2D-tiled: wave (cw = w>>1, ntw = w&1) owns c-strip [16cw,16cw+16) of the
// block's 64-c slice and n-half [32ntw, 32ntw+32): 1 c-tile x 2 n-tiles.
// Per k-step s: ONE V A-frag + TWO P B-frag reads -> 2 MFMAs.
// Wave P-read volume = 8 b128 (half of the old 16) -> LDS traffic halved.
__device__ __forceinline__ void pv_phase(const bf16x8 (&vf)[4],
        floatx4 (&oacc)[2], const u16* __restrict__ Ps,
        int lrow, int quad, int sw, int ntw)
{
    #pragma unroll
    for (int s = 0; s < 4; ++s) {
        int cb = (s << 3) + (quad << 1);
        bf16x8 pf0 = *(const bf16x8*)&Ps[(ntw*32 + lrow)*128 + ((cb ^ sw) << 2)];
        bf16x8 pf1 = *(const bf16x8*)&Ps[(ntw*32 + 16 + lrow)*128 + ((cb ^ sw) << 2)];
        __builtin_amdgcn_s_setprio(1);
        oacc[0] = __builtin_amdgcn_mfma_f32_16x16x32_bf16(vf[s], pf0, oacc[0], 0, 0, 0);
        oacc[1] = __builtin_amdgcn_mfma_f32_16x16x32_bf16(vf[s], pf1, oacc[1], 0, 0, 0);
        __builtin_amdgcn_s_setprio(0);
    }
}

// Full-M attention, c-split x4, 2 BLOCKS/CU:
// grid 512 = 64 ntiles x 2 b x 4 csplit; 512 threads = 8 waves; LDS 34 KB and
// VGPR<=128 (launch_bounds(512,4)) -> 2 co-resident INDEPENDENT blocks per CU.
// Blocks share no barriers: when one stalls at its P-barrier the other's waves
// fill the SIMD (the overlap v4's barrier-coupled wave-groups couldn't give).
// QK duplicated x4 (vs x2) so softmax denom stays block-local; P dbuf in LDS,
// one barrier/iter; PV uses 2D wave tiling (4 c-strips x 2 n-halves).
__launch_bounds__(512, 4)
__global__ void attn_v7(const u16* __restrict__ pk2, const u16* __restrict__ vt,
                        const float* __restrict__ qk, float* __restrict__ out) {
    const int bid = blockIdx.x;
    const int xcd = bid & 7;                        // presumed bid%8 -> XCD
    const int b   = xcd >> 2, cs = xcd & 3;         // XCD working set ~2MB: L2-fits
    const int ntile = bid >> 3;                     // 0..63
    const int tid = threadIdx.x, w = tid >> 6, l = tid & 63;
    const int lrow = l & 15, quad = l >> 4;
    const int n0 = ntile * NW;
    const int sw  = lrow << 1;                      // P XOR swizzle (keeps 16B pairs)
    const int cbw = (w << 2) + quad;                // QK write chunk = m_l>>2
    const int cw  = w >> 1, ntw = w & 1;            // PV 2D wave tile

    __shared__ __align__(16) u16 P[2][NW * 128];    // 2 x 16 KB
    __shared__ float sums_s[8][NW];

    // Q B-fragments: B[k=c][n]: n = n0+t*16+lrow, c = cc*32+quad*8+i
    bf16x8 qf[2][4];
    const float* qb = qk + (size_t)b * CK * NN + n0;
    #pragma unroll
    for (int cc = 0; cc < 2; ++cc)
        #pragma unroll
        for (int t = 0; t < 4; ++t)
            #pragma unroll
            for (int i = 0; i < 8; ++i) {
                int c = cc*32 + quad*8 + i;
                qf[cc][t][i] = (short)f2b(qb[(size_t)c*NN + t*16 + lrow]);
            }

    const u16* pkb  = pk2 + (size_t)b * (8*MM*8);
    const int  mrw  = w*16 + lrow;                  // K A-frag m-row
    // V A-frag row: c = cs*64 + cw*16 + lrow, m = kstep*32 + quad*8
    const u16* vrow = vt + ((size_t)b*CV + cs*64 + cw*16 + lrow)*MM + quad*8;

    floatx4 oacc[2];
    oacc[0] = (floatx4){0.f, 0.f, 0.f, 0.f};
    oacc[1] = (floatx4){0.f, 0.f, 0.f, 0.f};
    float sacc[4] = {0.f, 0.f, 0.f, 0.f};

    // ---- preamble: loads for iter 0, QK(0) -> P[0]
    bf16x8 k0 = *(const bf16x8*)(pkb + ((size_t)quad*MM + mrw)*8);
    bf16x8 k1 = *(const bf16x8*)(pkb + ((size_t)(quad+4)*MM + mrw)*8);
    bf16x8 vf[4];
    #pragma unroll
    for (int s = 0; s < 4; ++s)
        vf[s] = *(const bf16x8*)(vrow + s*32);
    qk_phase(k0, k1, qf, sacc, P[0], lrow, cbw, sw);

    for (int it = 0; it < NIT - 1; ++it) {
        __syncthreads();                            // P[it&1] complete
        const int mb2 = (it + 1) << 7;
        bf16x8 k0n = *(const bf16x8*)(pkb + ((size_t)quad*MM + mb2 + mrw)*8);
        bf16x8 k1n = *(const bf16x8*)(pkb + ((size_t)(quad+4)*MM + mb2 + mrw)*8);
        bf16x8 vn[4];
        #pragma unroll
        for (int s = 0; s < 4; ++s)
            vn[s] = *(const bf16x8*)(vrow + mb2 + s*32);
        pv_phase(vf, oacc, P[it & 1], lrow, quad, sw, ntw);
        qk_phase(k0n, k1n, qf, sacc, P[(it + 1) & 1], lrow, cbw, sw);
        #pragma unroll
        for (int s = 0; s < 4; ++s) vf[s] = vn[s];
    }
    __syncthreads();
    pv_phase(vf, oacc, P[(NIT - 1) & 1], lrow, quad, sw, ntw);

    // ---- softmax denominator: quad-reduce, then 8-wave LDS reduce
    #pragma unroll
    for (int t = 0; t < 4; ++t) {
        float v = sacc[t];
        v += __shfl_xor(v, 16, 64);
        v += __shfl_xor(v, 32, 64);
        if (l < 16) sums_s[w][t*16 + l] = v;
    }
    __syncthreads();
    float inv2[2];
    #pragma unroll
    for (int t2 = 0; t2 < 2; ++t2) {
        float d = 0.f;
        #pragma unroll
        for (int w2 = 0; w2 < 8; ++w2) d += sums_s[w2][ntw*32 + t2*16 + lrow];
        inv2[t2] = 1.0f / d;
    }

    // ---- normalized direct write: out[b, 256 + cs*64 + c_loc, n0 + ntw*32 + ...]
    float* ob = out + ((size_t)(b*512 + 256 + cs*64))*NN + n0 + ntw*32;
    #pragma unroll
    for (int t2 = 0; t2 < 2; ++t2)
        #pragma unroll
        for (int r = 0; r < 4; ++r) {
            int c_loc = cw*16 + quad*4 + r;
            ob[(size_t)c_loc*NN + t2*16 + lrow] = oacc[t2][r] * inv2[t2];
        }
}

// ======================= fallback (proven round-4) path =======================

__global__ void pool_v_f32(const float* __restrict__ src, float* __restrict__ out) {
    int e = blockIdx.x * 256 + threadIdx.x;
    int c = e & 255;
    int r = e >> 8;
    int ww = r & 31;  int hh = (r >> 5) & 31;
    int t  = (r >> 10) & 3;  int b = r >> 12;
    int m  = r & (MM - 1);
    const float* s = src + ((size_t)(((b*NT + t)*CV + c)*HH + 2*hh))*WW + 2*ww;
    out[(size_t)b*OUT_B + (size_t)m*CV + c] = fmaxf(fmaxf(s[0], s[1]), fmaxf(s[WW], s[WW+1]));
}

__global__ void pool_k_f32(const float* __restrict__ src, float* __restrict__ dst) {
    int e = blockIdx.x * 256 + threadIdx.x;
    int c = e & 63;
    int r = e >> 6;
    int ww = r & 31;  int hh = (r >> 5) & 31;
    int t  = (r >> 10) & 3;  int b = r >> 12;
    const float* s = src + ((size_t)(((b*NT + t)*CK + c)*HH + 2*hh))*WW + 2*ww;
    dst[e] = fmaxf(fmaxf(s[0], s[1]), fmaxf(s[WW], s[WW+1]));
}

__global__ void copy_qv_f32(const float4* __restrict__ src, float4* __restrict__ dst) {
    int u = blockIdx.x * 256 + threadIdx.x;
    int b  = u >> 18;
    int ru = u & 262143;
    dst[(size_t)b * (OUT_B/4) + ru] = src[u];
}

template<bool STAGED_K>
__launch_bounds__(256)
__global__ void attn_old(const float* __restrict__ pk,
                         const float* __restrict__ mk,
                         const float* __restrict__ qk,
                         float* __restrict__ out) {
    __shared__ __align__(16) float q_lds[CK][4];
    __shared__ __align__(16) float sarr[4][MM];
    __shared__ float inv_l[4];

    const int tid = threadIdx.x;
    const int blk = blockIdx.x;
    const int b   = blk >> 10;
    const int n0  = (blk & 1023) << 2;

    {
        int c = tid >> 2, qi = tid & 3;
        q_lds[c][qi] = qk[((size_t)(b*CK + c))*NN + n0 + qi];
    }
    __syncthreads();

    #pragma unroll
    for (int i = 0; i < 16; ++i) {
        int m = tid + (i << 8);
        float a0 = 0.f, a1 = 0.f, a2 = 0.f, a3 = 0.f;
        if (STAGED_K) {
            const float4* k4 = reinterpret_cast<const float4*>(pk + ((size_t)b*MM + m)*CK);
            #pragma unroll
            for (int cc = 0; cc < 16; ++cc) {
                float4 kv = k4[cc];
                int c = cc*4;
                float4 q0 = *reinterpret_cast<const float4*>(&q_lds[c][0]);
                float4 q1 = *reinterpret_cast<const float4*>(&q_lds[c+1][0]);
                float4 q2 = *reinterpret_cast<const float4*>(&q_lds[c+2][0]);
                float4 q3 = *reinterpret_cast<const float4*>(&q_lds[c+3][0]);
                a0 += kv.x*q0.x + kv.y*q1.x + kv.z*q2.x + kv.w*q3.x;
                a1 += kv.x*q0.y + kv.y*q1.y + kv.z*q2.y + kv.w*q3.y;
                a2 += kv.x*q0.z + kv.y*q1.z + kv.z*q2.z + kv.w*q3.z;
                a3 += kv.x*q0.w + kv.y*q1.w + kv.z*q2.w + kv.w*q3.w;
            }
        } else {
            int ww = m & 31, hh = (m >> 5) & 31, t = m >> 10;
            const float* base = mk + ((size_t)((b*NT + t)*CK)*HH + 2*hh)*WW + 2*ww;
            for (int c = 0; c < CK; ++c) {
                const float* s = base + (size_t)c*HH*WW;
                float kv = fmaxf(fmaxf(s[0], s[1]), fmaxf(s[WW], s[WW+1]));
                float4 q = *reinterpret_cast<const float4*>(&q_lds[c][0]);
                a0 += kv*q.x; a1 += kv*q.y; a2 += kv*q.z; a3 += kv*q.w;
            }
        }
        sarr[0][m] = a0*SCALE;
        sarr[1][m] = a1*SCALE;
        sarr[2][m] = a2*SCALE;
        sarr[3][m] = a3*SCALE;
    }
    __syncthreads();

    const int wave = tid >> 6, lane = tid & 63;
    float mx = -3.0e38f;
    for (int m = lane; m < MM; m += 64) mx = fmaxf(mx, sarr[wave][m]);
    #pragma unroll
    for (int off = 32; off > 0; off >>= 1) mx = fmaxf(mx, __shfl_xor(mx, off, 64));
    float ls = 0.f;
    for (int m = lane; m < MM; m += 64) {
        float p = __expf(sarr[wave][m] - mx);
        sarr[wave][m] = p;
        ls += p;
    }
    #pragma unroll
    for (int off = 32; off > 0; off >>= 1) ls += __shfl_xor(ls, off, 64);
    if (lane == 0) inv_l[wave] = 1.0f / ls;
    __syncthreads();

    const int c4 = lane;
    const float4* vb = reinterpret_cast<const float4*>(out + (size_t)b*OUT_B) + c4;
    const float* prow = sarr[wave];
    float a0 = 0.f, a1 = 0.f, a2 = 0.f, a3 = 0.f;
    for (int m = 0; m < MM; m += 4) {
        float4 p4 = *reinterpret_cast<const float4*>(prow + m);
        const float4* vp = vb + (size_t)m*(CV/4);
        float4 v0 = vp[0], v1 = vp[CV/4], v2 = vp[CV/2], v3 = vp[3*(CV/4)];
        a0 += p4.x*v0.x + p4.y*v1.x + p4.z*v2.x + p4.w*v3.x;
        a1 += p4.x*v0.y + p4.y*v1.y + p4.z*v2.y + p4.w*v3.y;
        a2 += p4.x*v0.z + p4.y*v1.z + p4.z*v2.z + p4.w*v3.z;
        a3 += p4.x*v0.w + p4.y*v1.w + p4.z*v2.w + p4.w*v3.w;
    }

    float inv = inv_l[wave];
    int n = n0 + wave;
    size_t ob = ((size_t)(b*512 + 256 + c4*4))*NN + n;
    out[ob]        = a0*inv;
    out[ob + NN]   = a1*inv;
    out[ob + 2*NN] = a2*inv;
    out[ob + 3*NN] = a3*inv;
}

// ================================ launcher ================================

extern "C" void kernel_launch(void* const* d_in, const int* in_sizes, int n_in,
                              void* d_out, int out_size, void* d_ws, size_t ws_size,
                              hipStream_t stream) {
    const float* mk = (const float*)d_in[0];
    const float* mv = (const float*)d_in[1];
    const float* qk = (const float*)d_in[2];
    const float* qv = (const float*)d_in[3];
    float* out = (float*)d_out;

    // fast-path ws layout: pk2 1MB | vt 4MB  (5 MB total)
    u16* pk2 = (u16*)d_ws;
    u16* vt  = pk2 + (size_t)NB*8*MM*8;                 // 524288 u16
    const size_t need = ((size_t)NB*8*MM*8 + (size_t)NB*CV*MM) * sizeof(u16);

    if (ws_size >= need) {
        prep<<<PRE_T/256, 256, 0, stream>>>(mk, mv, (const float4*)qv, pk2, vt, out);
        attn_v7<<<512, 512, 0, stream>>>(pk2, vt, qk, out);
    } else {
        const size_t pk_bytes = (size_t)NB*MM*CK*sizeof(float);
        const bool staged = (ws_size >= pk_bytes);
        float* pk = (float*)d_ws;
        pool_v_f32<<<(NB*MM*CV)/256, 256, 0, stream>>>(mv, out);
        if (staged) {
            pool_k_f32<<<(NB*MM*CK)/256, 256, 0, stream>>>(mk, pk);
            attn_old<true ><<<NB*(NN/4), 256, 0, stream>>>(pk, mk, qk, out);
        } else {
            attn_old<false><<<NB*(NN/4), 256, 0, stream>>>(pk, mk, qk, out);
        }
        copy_qv_f32<<<((NB*CV*HH*WW)/4)/256, 256, 0, stream>>>((const float4*)qv, (float4*)out);
    }
}

// Round 9
// 143.403 us; speedup vs baseline: 1.1351x; 1.1351x over previous
//
#include <hip/hip_runtime.h>
#include <hip/hip_bf16.h>
#include <math.h>

typedef unsigned short u16;
typedef unsigned int   u32;
typedef __attribute__((ext_vector_type(8))) short  bf16x8;
typedef __attribute__((ext_vector_type(4))) float  floatx4;

#define NB 2
#define NT 4
#define CK 64
#define CV 256
#define HH 64
#define WW 64
#define MM 4096    // NT*32*32
#define NN 4096    // HH*WW
#define SCALE 0.125f
#define SHIFT 4.0f
#define OUT_B 2097152      // f32 elems per batch in out (512*4096)
#define NW 64              // n-columns per attn block
#define ITG 16             // iters per block (m-half: 16 x 128 = 2048)
// exp(x*SCALE - SHIFT) = exp2(x*C1 + C2)
#define C1 0.18033688011112042f
#define C2 (-5.770780163555853f)

__device__ __forceinline__ u16 f2b(float f) {
    __hip_bfloat16 h = __float2bfloat16(f);
    union { __hip_bfloat16 h; u16 u; } v; v.h = h; return v.u;
}

// ============================ fast (MFMA) path ============================
// prep: K -> pk2[b][cblk(8)][m(4096)][8c]  (fragment-tiled, 16B stores)
//       V -> vt[b][c][m]                    (8B ushort4 stores)
//       qv -> out[:, 0:256, :, :]           (float4 copy)
#define PRE_K 65536        // NB*8*4096
#define PRE_V 589824       // + NB*CV*MM/4 (=524288)
#define PRE_T 1114112      // + NB*CV*HH*WW/4 (=524288)

__global__ void prep(const float* __restrict__ mk, const float* __restrict__ mv,
                     const float4* __restrict__ qv,
                     u16* __restrict__ pk2, u16* __restrict__ vt,
                     float* __restrict__ out) {
    int u = blockIdx.x * 256 + threadIdx.x;
    if (u < PRE_K) {
        // one thread = 8 c-values at one m -> coalesced float2 reads, 16B write
        int m = u & 4095, cb8 = (u >> 12) & 7, b = u >> 15;
        int t = m >> 10, hh = (m >> 5) & 31, ww = m & 31;
        const float* s0 = mk + ((size_t)((b*NT + t)*CK + cb8*8))*(HH*WW)
                             + (2*hh)*WW + 2*ww;
        bf16x8 fr;
        #pragma unroll
        for (int i = 0; i < 8; ++i) {
            const float* s = s0 + (size_t)i*(HH*WW);
            float2 r0 = *(const float2*)s;
            float2 r1 = *(const float2*)(s + WW);
            fr[i] = (short)f2b(fmaxf(fmaxf(r0.x, r0.y), fmaxf(r1.x, r1.y)));
        }
        *(bf16x8*)(pk2 + ((size_t)(b*8 + cb8)*MM + m)*8) = fr;
    } else if (u < PRE_V) {
        // one thread = 4 consecutive m at one c -> float4 reads, 8B write
        int u2 = u - PRE_K;
        int m4 = u2 & 1023, c = (u2 >> 10) & 255, b = u2 >> 18;
        int t = m4 >> 8, hh = (m4 >> 3) & 31, w8 = m4 & 7;
        const float* s0 = mv + ((size_t)((b*NT + t)*CV + c))*(HH*WW)
                             + (2*hh)*WW + 8*w8;
        float4 a0 = *(const float4*)(s0);
        float4 a1 = *(const float4*)(s0 + 4);
        float4 b0 = *(const float4*)(s0 + WW);
        float4 b1 = *(const float4*)(s0 + WW + 4);
        ushort4 r;
        r.x = f2b(fmaxf(fmaxf(a0.x, a0.y), fmaxf(b0.x, b0.y)));
        r.y = f2b(fmaxf(fmaxf(a0.z, a0.w), fmaxf(b0.z, b0.w)));
        r.z = f2b(fmaxf(fmaxf(a1.x, a1.y), fmaxf(b1.x, b1.y)));
        r.w = f2b(fmaxf(fmaxf(a1.z, a1.w), fmaxf(b1.z, b1.w)));
        *(ushort4*)(vt + ((size_t)(b*CV + c)*MM) + m4*4) = r;
    } else {
        int u3 = u - PRE_V;
        int b = u3 >> 18, ru = u3 & 262143;
        ((float4*)out)[(size_t)b*(OUT_B/4) + ru] = qv[u3];
    }
}

// ---- attn phases (identical to v3, the 57us best) ----
// QK: wave w owns m-rows [16w,16w+16) of the 128-m iter, all 64 n.
// S C-layout: n_l = t*16+lrow, m_l = 16w + quad*4 + r.
__device__ __forceinline__ void qk_phase(bf16x8 k0, bf16x8 k1,
        const bf16x8 (&qf)[2][4], float (&sacc)[4],
        u16* __restrict__ Pd, int lrow, int cbw, int sw)
{
    #pragma unroll
    for (int t = 0; t < 4; ++t) {
        floatx4 s = __builtin_amdgcn_mfma_f32_16x16x32_bf16(
                        k0, qf[0][t], (floatx4){0.f,0.f,0.f,0.f}, 0, 0, 0);
        s = __builtin_amdgcn_mfma_f32_16x16x32_bf16(k1, qf[1][t], s, 0, 0, 0);
        float p0 = exp2f(__builtin_fmaf(s[0], C1, C2));
        float p1 = exp2f(__builtin_fmaf(s[1], C1, C2));
        float p2 = exp2f(__builtin_fmaf(s[2], C1, C2));
        float p3 = exp2f(__builtin_fmaf(s[3], C1, C2));
        sacc[t] += (p0 + p1) + (p2 + p3);
        u32 d0 = (u32)f2b(p0) | ((u32)f2b(p1) << 16);
        u32 d1 = (u32)f2b(p2) | ((u32)f2b(p3) << 16);
        *(uint2*)&Pd[(t*16 + lrow)*128 + ((cbw ^ sw) << 2)] = make_uint2(d0, d1);
    }
}

// PV: wave w owns c-rows [16w,16w+16) of the block's 128-c half, all 64 n.
__device__ __forceinline__ void pv_phase(const bf16x8 (&vf)[4],
        floatx4 (&oacc)[4], const u16* __restrict__ Ps,
        int lrow, int quad, int sw)
{
    #pragma unroll
    for (int cc = 0; cc < 4; ++cc) {
        bf16x8 pf[4];
        #pragma unroll
        for (int t = 0; t < 4; ++t) {
            int cb = (cc << 3) + (quad << 1);
            pf[t] = *(const bf16x8*)&Ps[(t*16 + lrow)*128 + ((cb ^ sw) << 2)];
        }
        __builtin_amdgcn_s_setprio(1);
        #pragma unroll
        for (int t = 0; t < 4; ++t)
            oacc[t] = __builtin_amdgcn_mfma_f32_16x16x32_bf16(
                          vf[cc], pf[t], oacc[t], 0, 0, 0);
        __builtin_amdgcn_s_setprio(0);
    }
}

// v8 = v3's EXACT per-iter structure + m-split x2 -> 2 INDEPENDENT blocks/CU.
// grid 512 = 64nt x 2b x 2cs x 2ms; 512 threads = 8 waves; LDS 34KB/block and
// VGPR<=128 (launch_bounds(512,4)) -> 2 co-resident blocks per CU with NO
// shared barriers: while one block stalls (P-barrier / L2 latency) the other
// block's waves issue. Per-CU work is byte-identical to v3 (QK dup x2 total,
// same exp count, same LDS traffic & swizzle) - only schedule freedom changes.
// Cost: partial O (part) + denom (sums) round-trip combined in epilogue2.
__launch_bounds__(512, 4)
__global__ void attn_v8(const u16* __restrict__ pk2, const u16* __restrict__ vt,
                        const float* __restrict__ qk,
                        float* __restrict__ part, float* __restrict__ sums) {
    const int bid = blockIdx.x;
    const int xcd = bid & 7;                        // presumed bid%8 -> XCD
    const int b  = (xcd >> 2) & 1;                  // XCD working set ~1.75MB: L2-fits
    const int cs = (xcd >> 1) & 1;
    const int ms = xcd & 1;
    const int ntile = bid >> 3;                     // 0..63
    const int tid = threadIdx.x, w = tid >> 6, l = tid & 63;
    const int lrow = l & 15, quad = l >> 4;
    const int n0 = ntile * NW;
    const int sw  = lrow << 1;                      // P XOR swizzle (keeps 16B pairs)
    const int cbw = (w << 2) + quad;                // QK write chunk = m_l>>2
    const int mstart = ms << 11;                    // 2048*ms

    __shared__ __align__(16) u16 P[2][NW * 128];    // 2 x 16 KB
    __shared__ float sums_s[8][NW];

    // Q B-fragments: B[k=c][n]: n = n0+t*16+lrow, c = cc*32+quad*8+i
    bf16x8 qf[2][4];
    const float* qb = qk + (size_t)b * CK * NN + n0;
    #pragma unroll
    for (int cc = 0; cc < 2; ++cc)
        #pragma unroll
        for (int t = 0; t < 4; ++t)
            #pragma unroll
            for (int i = 0; i < 8; ++i) {
                int c = cc*32 + quad*8 + i;
                qf[cc][t][i] = (short)f2b(qb[(size_t)c*NN + t*16 + lrow]);
            }

    const u16* pkb  = pk2 + (size_t)b * (8*MM*8);
    const int  mrw  = mstart + w*16 + lrow;         // K A-frag m-row (global)
    const u16* vrow = vt + ((size_t)b*CV + cs*128 + w*16 + lrow)*MM
                         + mstart + quad*8;

    floatx4 oacc[4];
    #pragma unroll
    for (int t = 0; t < 4; ++t) oacc[t] = (floatx4){0.f, 0.f, 0.f, 0.f};
    float sacc[4] = {0.f, 0.f, 0.f, 0.f};

    // ---- preamble: loads for iter 0, QK(0) -> P[0]
    bf16x8 k0 = *(const bf16x8*)(pkb + ((size_t)quad*MM + mrw)*8);
    bf16x8 k1 = *(const bf16x8*)(pkb + ((size_t)(quad+4)*MM + mrw)*8);
    bf16x8 vf[4];
    #pragma unroll
    for (int cc = 0; cc < 4; ++cc)
        vf[cc] = *(const bf16x8*)(vrow + cc*32);
    qk_phase(k0, k1, qf, sacc, P[0], lrow, cbw, sw);

    for (int it = 0; it < ITG - 1; ++it) {
        __syncthreads();                            // P[it&1] complete
        const int mb2 = (it + 1) << 7;              // local m-offset of it+1
        bf16x8 k0n = *(const bf16x8*)(pkb + ((size_t)quad*MM + mb2 + mrw)*8);
        bf16x8 k1n = *(const bf16x8*)(pkb + ((size_t)(quad+4)*MM + mb2 + mrw)*8);
        bf16x8 vn[4];
        #pragma unroll
        for (int cc = 0; cc < 4; ++cc)
            vn[cc] = *(const bf16x8*)(vrow + mb2 + cc*32);
        pv_phase(vf, oacc, P[it & 1], lrow, quad, sw);
        qk_phase(k0n, k1n, qf, sacc, P[(it + 1) & 1], lrow, cbw, sw);
        #pragma unroll
        for (int cc = 0; cc < 4; ++cc) vf[cc] = vn[cc];
    }
    __syncthreads();
    pv_phase(vf, oacc, P[(ITG - 1) & 1], lrow, quad, sw);

    // ---- partial softmax denominator: quad-reduce, then 8-wave LDS reduce
    #pragma unroll
    for (int t = 0; t < 4; ++t) {
        float v = sacc[t];
        v += __shfl_xor(v, 16, 64);
        v += __shfl_xor(v, 32, 64);
        if (l < 16) sums_s[w][t*16 + l] = v;
    }
    __syncthreads();

    // ---- write partial O tile [128c][64n]
    float* pb = part + ((size_t)((((ms*NB + b)*2 + cs)*64) + ntile)) * (128*64);
    #pragma unroll
    for (int t = 0; t < 4; ++t)
        #pragma unroll
        for (int r = 0; r < 4; ++r) {
            int c_loc = w*16 + quad*4 + r;
            pb[c_loc*64 + t*16 + lrow] = oacc[t][r];
        }
    // sums are cs-independent (QK duplicated): only cs==0 stores
    if (cs == 0 && tid < 64) {
        float sv = 0.f;
        #pragma unroll
        for (int w2 = 0; w2 < 8; ++w2) sv += sums_s[w2][tid];
        sums[((size_t)((ms*NB + b)*64 + ntile))*64 + tid] = sv;
    }
}

// combine m-split partials + normalize: O = (part0+part1)/(d0+d1)
__global__ void epilogue2(const float* __restrict__ part,
                          const float* __restrict__ sums,
                          float* __restrict__ out) {
    int e = blockIdx.x * 256 + threadIdx.x;        // 524288 = 2b*256c*1024n4
    int nl4 = e & 15;
    int nt  = (e >> 4) & 63;
    int c   = (e >> 10) & 255;
    int b   = e >> 18;
    int cs = c >> 7, cl = c & 127;
    const float4* p4 = (const float4*)part;
    const float4* s4 = (const float4*)sums;
    size_t t0 = (size_t)(((0*NB + b)*2 + cs)*64 + nt);
    size_t t1 = (size_t)(((1*NB + b)*2 + cs)*64 + nt);
    float4 u0 = p4[t0*2048 + cl*16 + nl4];
    float4 u1 = p4[t1*2048 + cl*16 + nl4];
    float4 d0 = s4[((size_t)((0*NB + b)*64 + nt))*16 + nl4];
    float4 d1 = s4[((size_t)((1*NB + b)*64 + nt))*16 + nl4];
    float4 r;
    r.x = (u0.x + u1.x) / (d0.x + d1.x);
    r.y = (u0.y + u1.y) / (d0.y + d1.y);
    r.z = (u0.z + u1.z) / (d0.z + d1.z);
    r.w = (u0.w + u1.w) / (d0.w + d1.w);
    ((float4*)out)[(size_t)(b*512 + 256 + c)*1024 + nt*16 + nl4] = r;
}

// ======================= fallback (proven round-4) path =======================

__global__ void pool_v_f32(const float* __restrict__ src, float* __restrict__ out) {
    int e = blockIdx.x * 256 + threadIdx.x;
    int c = e & 255;
    int r = e >> 8;
    int ww = r & 31;  int hh = (r >> 5) & 31;
    int t  = (r >> 10) & 3;  int b = r >> 12;
    int m  = r & (MM - 1);
    const float* s = src + ((size_t)(((b*NT + t)*CV + c)*HH + 2*hh))*WW + 2*ww;
    out[(size_t)b*OUT_B + (size_t)m*CV + c] = fmaxf(fmaxf(s[0], s[1]), fmaxf(s[WW], s[WW+1]));
}

__global__ void pool_k_f32(const float* __restrict__ src, float* __restrict__ dst) {
    int e = blockIdx.x * 256 + threadIdx.x;
    int c = e & 63;
    int r = e >> 6;
    int ww = r & 31;  int hh = (r >> 5) & 31;
    int t  = (r >> 10) & 3;  int b = r >> 12;
    const float* s = src + ((size_t)(((b*NT + t)*CK + c)*HH + 2*hh))*WW + 2*ww;
    dst[e] = fmaxf(fmaxf(s[0], s[1]), fmaxf(s[WW], s[WW+1]));
}

__global__ void copy_qv_f32(const float4* __restrict__ src, float4* __restrict__ dst) {
    int u = blockIdx.x * 256 + threadIdx.x;
    int b  = u >> 18;
    int ru = u & 262143;
    dst[(size_t)b * (OUT_B/4) + ru] = src[u];
}

template<bool STAGED_K>
__launch_bounds__(256)
__global__ void attn_old(const float* __restrict__ pk,
                         const float* __restrict__ mk,
                         const float* __restrict__ qk,
                         float* __restrict__ out) {
    __shared__ __align__(16) float q_lds[CK][4];
    __shared__ __align__(16) float sarr[4][MM];
    __shared__ float inv_l[4];

    const int tid = threadIdx.x;
    const int blk = blockIdx.x;
    const int b   = blk >> 10;
    const int n0  = (blk & 1023) << 2;

    {
        int c = tid >> 2, qi = tid & 3;
        q_lds[c][qi] = qk[((size_t)(b*CK + c))*NN + n0 + qi];
    }
    __syncthreads();

    #pragma unroll
    for (int i = 0; i < 16; ++i) {
        int m = tid + (i << 8);
        float a0 = 0.f, a1 = 0.f, a2 = 0.f, a3 = 0.f;
        if (STAGED_K) {
            const float4* k4 = reinterpret_cast<const float4*>(pk + ((size_t)b*MM + m)*CK);
            #pragma unroll
            for (int cc = 0; cc < 16; ++cc) {
                float4 kv = k4[cc];
                int c = cc*4;
                float4 q0 = *reinterpret_cast<const float4*>(&q_lds[c][0]);
                float4 q1 = *reinterpret_cast<const float4*>(&q_lds[c+1][0]);
                float4 q2 = *reinterpret_cast<const float4*>(&q_lds[c+2][0]);
                float4 q3 = *reinterpret_cast<const float4*>(&q_lds[c+3][0]);
                a0 += kv.x*q0.x + kv.y*q1.x + kv.z*q2.x + kv.w*q3.x;
                a1 += kv.x*q0.y + kv.y*q1.y + kv.z*q2.y + kv.w*q3.y;
                a2 += kv.x*q0.z + kv.y*q1.z + kv.z*q2.z + kv.w*q3.z;
                a3 += kv.x*q0.w + kv.y*q1.w + kv.z*q2.w + kv.w*q3.w;
            }
        } else {
            int ww = m & 31, hh = (m >> 5) & 31, t = m >> 10;
            const float* base = mk + ((size_t)((b*NT + t)*CK)*HH + 2*hh)*WW + 2*ww;
            for (int c = 0; c < CK; ++c) {
                const float* s = base + (size_t)c*HH*WW;
                float kv = fmaxf(fmaxf(s[0], s[1]), fmaxf(s[WW], s[WW+1]));
                float4 q = *reinterpret_cast<const float4*>(&q_lds[c][0]);
                a0 += kv*q.x; a1 += kv*q.y; a2 += kv*q.z; a3 += kv*q.w;
            }
        }
        sarr[0][m] = a0*SCALE;
        sarr[1][m] = a1*SCALE;
        sarr[2][m] = a2*SCALE;
        sarr[3][m] = a3*SCALE;
    }
    __syncthreads();

    const int wave = tid >> 6, lane = tid & 63;
    float mx = -3.0e38f;
    for (int m = lane; m < MM; m += 64) mx = fmaxf(mx, sarr[wave][m]);
    #pragma unroll
    for (int off = 32; off > 0; off >>= 1) mx = fmaxf(mx, __shfl_xor(mx, off, 64));
    float ls = 0.f;
    for (int m = lane; m < MM; m += 64) {
        float p = __expf(sarr[wave][m] - mx);
        sarr[wave][m] = p;
        ls += p;
    }
    #pragma unroll
    for (int off = 32; off > 0; off >>= 1) ls += __shfl_xor(ls, off, 64);
    if (lane == 0) inv_l[wave] = 1.0f / ls;
    __syncthreads();

    const int c4 = lane;
    const float4* vb = reinterpret_cast<const float4*>(out + (size_t)b*OUT_B) + c4;
    const float* prow = sarr[wave];
    float a0 = 0.f, a1 = 0.f, a2 = 0.f, a3 = 0.f;
    for (int m = 0; m < MM; m += 4) {
        float4 p4 = *reinterpret_cast<const float4*>(prow + m);
        const float4* vp = vb + (size_t)m*(CV/4);
        float4 v0 = vp[0], v1 = vp[CV/4], v2 = vp[CV/2], v3 = vp[3*(CV/4)];
        a0 += p4.x*v0.x + p4.y*v1.x + p4.z*v2.x + p4.w*v3.x;
        a1 += p4.x*v0.y + p4.y*v1.y + p4.z*v2.y + p4.w*v3.y;
        a2 += p4.x*v0.z + p4.y*v1.z + p4.z*v2.z + p4.w*v3.z;
        a3 += p4.x*v0.w + p4.y*v1.w + p4.z*v2.w + p4.w*v3.w;
    }

    float inv = inv_l[wave];
    int n = n0 + wave;
    size_t ob = ((size_t)(b*512 + 256 + c4*4))*NN + n;
    out[ob]        = a0*inv;
    out[ob + NN]   = a1*inv;
    out[ob + 2*NN] = a2*inv;
    out[ob + 3*NN] = a3*inv;
}

// ================================ launcher ================================

extern "C" void kernel_launch(void* const* d_in, const int* in_sizes, int n_in,
                              void* d_out, int out_size, void* d_ws, size_t ws_size,
                              hipStream_t stream) {
    const float* mk = (const float*)d_in[0];
    const float* mv = (const float*)d_in[1];
    const float* qk = (const float*)d_in[2];
    const float* qv = (const float*)d_in[3];
    float* out = (float*)d_out;

    // fast-path ws layout: pk2 1MB | vt 4MB | part 16MB | sums 64KB (~21.07MB)
    u16* pk2 = (u16*)d_ws;
    u16* vt  = pk2 + (size_t)NB*8*MM*8;                 // 524288 u16
    float* part = (float*)(vt + (size_t)NB*CV*MM);      // 4194304 f32
    float* sums = part + 4194304;                       // 16384 f32
    const size_t need = ((size_t)NB*8*MM*8 + (size_t)NB*CV*MM) * sizeof(u16)
                      + (4194304 + 16384) * sizeof(float);

    if (ws_size >= need) {
        prep<<<PRE_T/256, 256, 0, stream>>>(mk, mv, (const float4*)qv, pk2, vt, out);
        attn_v8<<<512, 512, 0, stream>>>(pk2, vt, qk, part, sums);
        epilogue2<<<524288/256, 256, 0, stream>>>(part, sums, out);
    } else {
        const size_t pk_bytes = (size_t)NB*MM*CK*sizeof(float);
        const bool staged = (ws_size >= pk_bytes);
        float* pk = (float*)d_ws;
        pool_v_f32<<<(NB*MM*CV)/256, 256, 0, stream>>>(mv, out);
        if (staged) {
            pool_k_f32<<<(NB*MM*CK)/256, 256, 0, stream>>>(mk, pk);
            attn_old<true ><<<NB*(NN/4), 256, 0, stream>>>(pk, mk, qk, out);
        } else {
            attn_old<false><<<NB*(NN/4), 256, 0, stream>>>(pk, mk, qk, out);
        }
        copy_qv_f32<<<((NB*CV*HH*WW)/4)/256, 256, 0, stream>>>((const float4*)qv, (float4*)out);
    }
}

// Round 10
// 141.369 us; speedup vs baseline: 1.1515x; 1.0144x over previous
//
#include <hip/hip_runtime.h>
#include <hip/hip_bf16.h>
#include <math.h>

typedef unsigned short u16;
typedef unsigned int   u32;
typedef __attribute__((ext_vector_type(8))) short  bf16x8;
typedef __attribute__((ext_vector_type(4))) float  floatx4;

#define NB 2
#define NT 4
#define CK 64
#define CV 256
#define HH 64
#define WW 64
#define MM 4096    // NT*32*32
#define NN 4096    // HH*WW
#define SCALE 0.125f
#define SHIFT 4.0f
#define OUT_B 2097152      // f32 elems per batch in out (512*4096)
#define NW 64              // n-columns per attn block
#define NIT 32             // MM / 128
// exp(x*SCALE - SHIFT) = exp2(x*C1 + C2)
#define C1 0.18033688011112042f
#define C2 (-5.770780163555853f)

__device__ __forceinline__ u16 f2b(float f) {
    __hip_bfloat16 h = __float2bfloat16(f);
    union { __hip_bfloat16 h; u16 u; } v; v.h = h; return v.u;
}

// raw transcendental: D = 2^S0 (1 instr vs ~6-instr ocml exp2f w/o fast-math)
__device__ __forceinline__ float fexp2(float x) {
    float r;
    asm("v_exp_f32 %0, %1" : "=v"(r) : "v"(x));
    return r;
}
// packed bf16 convert: lo16 = cvt(a), hi16 = cvt(b) (1 instr vs ~12)
__device__ __forceinline__ u32 cvtpk_bf16(float a, float b) {
    u32 r;
    asm("v_cvt_pk_bf16_f32 %0, %1, %2" : "=v"(r) : "v"(a), "v"(b));
    return r;
}

// ============================ fast (MFMA) path ============================
// prep: K -> pk2[b][cblk(8)][m(4096)][8c]  (fragment-tiled, 16B stores)
//       V -> vt[b][c][m]                    (8B ushort4 stores)
//       qv -> out[:, 0:256, :, :]           (float4 copy)
#define PRE_K 65536        // NB*8*4096
#define PRE_V 589824       // + NB*CV*MM/4 (=524288)
#define PRE_T 1114112      // + NB*CV*HH*WW/4 (=524288)

__global__ void prep(const float* __restrict__ mk, const float* __restrict__ mv,
                     const float4* __restrict__ qv,
                     u16* __restrict__ pk2, u16* __restrict__ vt,
                     float* __restrict__ out) {
    int u = blockIdx.x * 256 + threadIdx.x;
    if (u < PRE_K) {
        // one thread = 8 c-values at one m -> coalesced float2 reads, 16B write
        int m = u & 4095, cb8 = (u >> 12) & 7, b = u >> 15;
        int t = m >> 10, hh = (m >> 5) & 31, ww = m & 31;
        const float* s0 = mk + ((size_t)((b*NT + t)*CK + cb8*8))*(HH*WW)
                             + (2*hh)*WW + 2*ww;
        bf16x8 fr;
        #pragma unroll
        for (int i = 0; i < 8; ++i) {
            const float* s = s0 + (size_t)i*(HH*WW);
            float2 r0 = *(const float2*)s;
            float2 r1 = *(const float2*)(s + WW);
            fr[i] = (short)f2b(fmaxf(fmaxf(r0.x, r0.y), fmaxf(r1.x, r1.y)));
        }
        *(bf16x8*)(pk2 + ((size_t)(b*8 + cb8)*MM + m)*8) = fr;
    } else if (u < PRE_V) {
        // one thread = 4 consecutive m at one c -> float4 reads, 8B write
        int u2 = u - PRE_K;
        int m4 = u2 & 1023, c = (u2 >> 10) & 255, b = u2 >> 18;
        int t = m4 >> 8, hh = (m4 >> 3) & 31, w8 = m4 & 7;
        const float* s0 = mv + ((size_t)((b*NT + t)*CV + c))*(HH*WW)
                             + (2*hh)*WW + 8*w8;
        float4 a0 = *(const float4*)(s0);
        float4 a1 = *(const float4*)(s0 + 4);
        float4 b0 = *(const float4*)(s0 + WW);
        float4 b1 = *(const float4*)(s0 + WW + 4);
        ushort4 r;
        r.x = f2b(fmaxf(fmaxf(a0.x, a0.y), fmaxf(b0.x, b0.y)));
        r.y = f2b(fmaxf(fmaxf(a0.z, a0.w), fmaxf(b0.z, b0.w)));
        r.z = f2b(fmaxf(fmaxf(a1.x, a1.y), fmaxf(b1.x, b1.y)));
        r.w = f2b(fmaxf(fmaxf(a1.z, a1.w), fmaxf(b1.z, b1.w)));
        *(ushort4*)(vt + ((size_t)(b*CV + c)*MM) + m4*4) = r;
    } else {
        int u3 = u - PRE_V;
        int b = u3 >> 18, ru = u3 & 262143;
        ((float4*)out)[(size_t)b*(OUT_B/4) + ru] = qv[u3];
    }
}

// ---- attn phases (v3 structure; VALU-THIN epilogue) ----
// QK: wave w owns m-rows [16w,16w+16) of the 128-m iter, all 64 n.
// S C-layout: n_l = t*16+lrow, m_l = 16w + quad*4 + r.
__device__ __forceinline__ void qk_phase(bf16x8 k0, bf16x8 k1,
        const bf16x8 (&qf)[2][4], float (&sacc)[4],
        u16* __restrict__ Pd, int lrow, int cbw, int sw)
{
    #pragma unroll
    for (int t = 0; t < 4; ++t) {
        floatx4 s = __builtin_amdgcn_mfma_f32_16x16x32_bf16(
                        k0, qf[0][t], (floatx4){0.f,0.f,0.f,0.f}, 0, 0, 0);
        s = __builtin_amdgcn_mfma_f32_16x16x32_bf16(k1, qf[1][t], s, 0, 0, 0);
        float p0 = fexp2(__builtin_fmaf(s[0], C1, C2));
        float p1 = fexp2(__builtin_fmaf(s[1], C1, C2));
        float p2 = fexp2(__builtin_fmaf(s[2], C1, C2));
        float p3 = fexp2(__builtin_fmaf(s[3], C1, C2));
        sacc[t] += (p0 + p1) + (p2 + p3);
        u32 d0 = cvtpk_bf16(p0, p1);
        u32 d1 = cvtpk_bf16(p2, p3);
        *(uint2*)&Pd[(t*16 + lrow)*128 + ((cbw ^ sw) << 2)] = make_uint2(d0, d1);
    }
}

// PV: wave w owns c-rows [16w,16w+16) of the block's 128-c half, all 64 n.
__device__ __forceinline__ void pv_phase(const bf16x8 (&vf)[4],
        floatx4 (&oacc)[4], const u16* __restrict__ Ps,
        int lrow, int quad, int sw)
{
    #pragma unroll
    for (int cc = 0; cc < 4; ++cc) {
        bf16x8 pf[4];
        #pragma unroll
        for (int t = 0; t < 4; ++t) {
            int cb = (cc << 3) + (quad << 1);
            pf[t] = *(const bf16x8*)&Ps[(t*16 + lrow)*128 + ((cb ^ sw) << 2)];
        }
        __builtin_amdgcn_s_setprio(1);
        #pragma unroll
        for (int t = 0; t < 4; ++t)
            oacc[t] = __builtin_amdgcn_mfma_f32_16x16x32_bf16(
                          vf[cc], pf[t], oacc[t], 0, 0, 0);
        __builtin_amdgcn_s_setprio(0);
    }
}

// Full-M attention, c-split PV (v3 = best structure, 56.8us), VALU-thin QK:
// grid 256 = 64 ntiles x 2 b x 2 csplit; 512 threads = 8 waves.
// QK duplicated across csplit so softmax denom is block-local -> direct
// normalized write, no epilogue. P double-buffered, ONE barrier/iter.
__launch_bounds__(512, 2)
__global__ void attn_v9(const u16* __restrict__ pk2, const u16* __restrict__ vt,
                        const float* __restrict__ qk, float* __restrict__ out) {
    const int bid = blockIdx.x;
    const int xcd = bid & 7, grp = bid >> 3;        // presumed bid%8 -> XCD
    const int b   = xcd >> 2, cs = (xcd >> 1) & 1;  // XCD's 1.5 MB K+V slice L2-fits
    const int ntile = (xcd & 1) * 32 + grp;
    const int tid = threadIdx.x, w = tid >> 6, l = tid & 63;
    const int lrow = l & 15, quad = l >> 4;
    const int n0 = ntile * NW;
    const int sw  = lrow << 1;                      // XOR swizzle (keeps 16B pairs)
    const int cbw = (w << 2) + quad;                // QK write chunk = m_l>>2

    __shared__ __align__(16) u16 P[2][NW * 128];    // 2 x 16 KB, row=n_l (256 B)
    __shared__ float sums_s[8][NW];

    // Q B-fragments: B[k=c][n]: n = n0+t*16+lrow, c = cc*32+quad*8+i
    bf16x8 qf[2][4];
    const float* qb = qk + (size_t)b * CK * NN + n0;
    #pragma unroll
    for (int cc = 0; cc < 2; ++cc)
        #pragma unroll
        for (int t = 0; t < 4; ++t)
            #pragma unroll
            for (int i = 0; i < 8; ++i) {
                int c = cc*32 + quad*8 + i;
                qf[cc][t][i] = (short)f2b(qb[(size_t)c*NN + t*16 + lrow]);
            }

    const u16* pkb  = pk2 + (size_t)b * (8*MM*8);
    const int  mrw  = w*16 + lrow;                  // K A-frag m-row offset
    const u16* vrow = vt + ((size_t)b*CV + cs*128 + w*16 + lrow)*MM + quad*8;

    floatx4 oacc[4];
    #pragma unroll
    for (int t = 0; t < 4; ++t) oacc[t] = (floatx4){0.f, 0.f, 0.f, 0.f};
    float sacc[4] = {0.f, 0.f, 0.f, 0.f};

    // ---- preamble: loads for iter 0, QK(0) -> P[0]
    bf16x8 k0 = *(const bf16x8*)(pkb + ((size_t)quad*MM + mrw)*8);
    bf16x8 k1 = *(const bf16x8*)(pkb + ((size_t)(quad+4)*MM + mrw)*8);
    bf16x8 vf[4];
    #pragma unroll
    for (int cc = 0; cc < 4; ++cc)
        vf[cc] = *(const bf16x8*)(vrow + cc*32);
    qk_phase(k0, k1, qf, sacc, P[0], lrow, cbw, sw);

    for (int it = 0; it < NIT - 1; ++it) {
        __syncthreads();                            // P[it&1] complete
        const int mb2 = (it + 1) << 7;
        // unconditional prefetch of iter it+1 (latency hides under PV)
        bf16x8 k0n = *(const bf16x8*)(pkb + ((size_t)quad*MM + mb2 + mrw)*8);
        bf16x8 k1n = *(const bf16x8*)(pkb + ((size_t)(quad+4)*MM + mb2 + mrw)*8);
        bf16x8 vn[4];
        #pragma unroll
        for (int cc = 0; cc < 4; ++cc)
            vn[cc] = *(const bf16x8*)(vrow + mb2 + cc*32);
        pv_phase(vf, oacc, P[it & 1], lrow, quad, sw);
        qk_phase(k0n, k1n, qf, sacc, P[(it + 1) & 1], lrow, cbw, sw);
        #pragma unroll
        for (int cc = 0; cc < 4; ++cc) vf[cc] = vn[cc];
    }
    __syncthreads();
    pv_phase(vf, oacc, P[(NIT - 1) & 1], lrow, quad, sw);

    // ---- softmax denominator: quad-reduce, then 8-wave LDS reduce
    #pragma unroll
    for (int t = 0; t < 4; ++t) {
        float v = sacc[t];
        v += __shfl_xor(v, 16, 64);
        v += __shfl_xor(v, 32, 64);
        if (l < 16) sums_s[w][t*16 + l] = v;
    }
    __syncthreads();
    float inv[4];
    #pragma unroll
    for (int t = 0; t < 4; ++t) {
        float d = 0.f;
        #pragma unroll
        for (int w2 = 0; w2 < 8; ++w2) d += sums_s[w2][t*16 + lrow];
        inv[t] = 1.0f / d;
    }

    // ---- normalized direct write: out[b, 256 + cs*128 + c_loc, n0 + n_l]
    float* ob = out + ((size_t)(b*512 + 256 + cs*128))*NN + n0;
    #pragma unroll
    for (int t = 0; t < 4; ++t)
        #pragma unroll
        for (int r = 0; r < 4; ++r) {
            int c_loc = w*16 + quad*4 + r;
            ob[(size_t)c_loc*NN + t*16 + lrow] = oacc[t][r] * inv[t];
        }
}

// ======================= fallback (proven round-4) path =======================

__global__ void pool_v_f32(const float* __restrict__ src, float* __restrict__ out) {
    int e = blockIdx.x * 256 + threadIdx.x;
    int c = e & 255;
    int r = e >> 8;
    int ww = r & 31;  int hh = (r >> 5) & 31;
    int t  = (r >> 10) & 3;  int b = r >> 12;
    int m  = r & (MM - 1);
    const float* s = src + ((size_t)(((b*NT + t)*CV + c)*HH + 2*hh))*WW + 2*ww;
    out[(size_t)b*OUT_B + (size_t)m*CV + c] = fmaxf(fmaxf(s[0], s[1]), fmaxf(s[WW], s[WW+1]));
}

__global__ void pool_k_f32(const float* __restrict__ src, float* __restrict__ dst) {
    int e = blockIdx.x * 256 + threadIdx.x;
    int c = e & 63;
    int r = e >> 6;
    int ww = r & 31;  int hh = (r >> 5) & 31;
    int t  = (r >> 10) & 3;  int b = r >> 12;
    const float* s = src + ((size_t)(((b*NT + t)*CK + c)*HH + 2*hh))*WW + 2*ww;
    dst[e] = fmaxf(fmaxf(s[0], s[1]), fmaxf(s[WW], s[WW+1]));
}

__global__ void copy_qv_f32(const float4* __restrict__ src, float4* __restrict__ dst) {
    int u = blockIdx.x * 256 + threadIdx.x;
    int b  = u >> 18;
    int ru = u & 262143;
    dst[(size_t)b * (OUT_B/4) + ru] = src[u];
}

template<bool STAGED_K>
__launch_bounds__(256)
__global__ void attn_old(const float* __restrict__ pk,
                         const float* __restrict__ mk,
                         const float* __restrict__ qk,
                         float* __restrict__ out) {
    __shared__ __align__(16) float q_lds[CK][4];
    __shared__ __align__(16) float sarr[4][MM];
    __shared__ float inv_l[4];

    const int tid = threadIdx.x;
    const int blk = blockIdx.x;
    const int b   = blk >> 10;
    const int n0  = (blk & 1023) << 2;

    {
        int c = tid >> 2, qi = tid & 3;
        q_lds[c][qi] = qk[((size_t)(b*CK + c))*NN + n0 + qi];
    }
    __syncthreads();

    #pragma unroll
    for (int i = 0; i < 16; ++i) {
        int m = tid + (i << 8);
        float a0 = 0.f, a1 = 0.f, a2 = 0.f, a3 = 0.f;
        if (STAGED_K) {
            const float4* k4 = reinterpret_cast<const float4*>(pk + ((size_t)b*MM + m)*CK);
            #pragma unroll
            for (int cc = 0; cc < 16; ++cc) {
                float4 kv = k4[cc];
                int c = cc*4;
                float4 q0 = *reinterpret_cast<const float4*>(&q_lds[c][0]);
                float4 q1 = *reinterpret_cast<const float4*>(&q_lds[c+1][0]);
                float4 q2 = *reinterpret_cast<const float4*>(&q_lds[c+2][0]);
                float4 q3 = *reinterpret_cast<const float4*>(&q_lds[c+3][0]);
                a0 += kv.x*q0.x + kv.y*q1.x + kv.z*q2.x + kv.w*q3.x;
                a1 += kv.x*q0.y + kv.y*q1.y + kv.z*q2.y + kv.w*q3.y;
                a2 += kv.x*q0.z + kv.y*q1.z + kv.z*q2.z + kv.w*q3.z;
                a3 += kv.x*q0.w + kv.y*q1.w + kv.z*q2.w + kv.w*q3.w;
            }
        } else {
            int ww = m & 31, hh = (m >> 5) & 31, t = m >> 10;
            const float* base = mk + ((size_t)((b*NT + t)*CK)*HH + 2*hh)*WW + 2*ww;
            for (int c = 0; c < CK; ++c) {
                const float* s = base + (size_t)c*HH*WW;
                float kv = fmaxf(fmaxf(s[0], s[1]), fmaxf(s[WW], s[WW+1]));
                float4 q = *reinterpret_cast<const float4*>(&q_lds[c][0]);
                a0 += kv*q.x; a1 += kv*q.y; a2 += kv*q.z; a3 += kv*q.w;
            }
        }
        sarr[0][m] = a0*SCALE;
        sarr[1][m] = a1*SCALE;
        sarr[2][m] = a2*SCALE;
        sarr[3][m] = a3*SCALE;
    }
    __syncthreads();

    const int wave = tid >> 6, lane = tid & 63;
    float mx = -3.0e38f;
    for (int m = lane; m < MM; m += 64) mx = fmaxf(mx, sarr[wave][m]);
    #pragma unroll
    for (int off = 32; off > 0; off >>= 1) mx = fmaxf(mx, __shfl_xor(mx, off, 64));
    float ls = 0.f;
    for (int m = lane; m < MM; m += 64) {
        float p = __expf(sarr[wave][m] - mx);
        sarr[wave][m] = p;
        ls += p;
    }
    #pragma unroll
    for (int off = 32; off > 0; off >>= 1) ls += __shfl_xor(ls, off, 64);
    if (lane == 0) inv_l[wave] = 1.0f / ls;
    __syncthreads();

    const int c4 = lane;
    const float4* vb = reinterpret_cast<const float4*>(out + (size_t)b*OUT_B) + c4;
    const float* prow = sarr[wave];
    float a0 = 0.f, a1 = 0.f, a2 = 0.f, a3 = 0.f;
    for (int m = 0; m < MM; m += 4) {
        float4 p4 = *reinterpret_cast<const float4*>(prow + m);
        const float4* vp = vb + (size_t)m*(CV/4);
        float4 v0 = vp[0], v1 = vp[CV/4], v2 = vp[CV/2], v3 = vp[3*(CV/4)];
        a0 += p4.x*v0.x + p4.y*v1.x + p4.z*v2.x + p4.w*v3.x;
        a1 += p4.x*v0.y + p4.y*v1.y + p4.z*v2.y + p4.w*v3.y;
        a2 += p4.x*v0.z + p4.y*v1.z + p4.z*v2.z + p4.w*v3.z;
        a3 += p4.x*v0.w + p4.y*v1.w + p4.z*v2.w + p4.w*v3.w;
    }

    float inv = inv_l[wave];
    int n = n0 + wave;
    size_t ob = ((size_t)(b*512 + 256 + c4*4))*NN + n;
    out[ob]        = a0*inv;
    out[ob + NN]   = a1*inv;
    out[ob + 2*NN] = a2*inv;
    out[ob + 3*NN] = a3*inv;
}

// ================================ launcher ================================

extern "C" void kernel_launch(void* const* d_in, const int* in_sizes, int n_in,
                              void* d_out, int out_size, void* d_ws, size_t ws_size,
                              hipStream_t stream) {
    const float* mk = (const float*)d_in[0];
    const float* mv = (const float*)d_in[1];
    const float* qk = (const float*)d_in[2];
    const float* qv = (const float*)d_in[3];
    float* out = (float*)d_out;

    // fast-path ws layout: pk2 1MB | vt 4MB  (5 MB total)
    u16* pk2 = (u16*)d_ws;
    u16* vt  = pk2 + (size_t)NB*8*MM*8;                 // 524288 u16
    const size_t need = ((size_t)NB*8*MM*8 + (size_t)NB*CV*MM) * sizeof(u16);

    if (ws_size >= need) {
        prep<<<PRE_T/256, 256, 0, stream>>>(mk, mv, (const float4*)qv, pk2, vt, out);
        attn_v9<<<256, 512, 0, stream>>>(pk2, vt, qk, out);
    } else {
        const size_t pk_bytes = (size_t)NB*MM*CK*sizeof(float);
        const bool staged = (ws_size >= pk_bytes);
        float* pk = (float*)d_ws;
        pool_v_f32<<<(NB*MM*CV)/256, 256, 0, stream>>>(mv, out);
        if (staged) {
            pool_k_f32<<<(NB*MM*CK)/256, 256, 0, stream>>>(mk, pk);
            attn_old<true ><<<NB*(NN/4), 256, 0, stream>>>(pk, mk, qk, out);
        } else {
            attn_old<false><<<NB*(NN/4), 256, 0, stream>>>(pk, mk, qk, out);
        }
        copy_qv_f32<<<((NB*CV*HH*WW)/4)/256, 256, 0, stream>>>((const float4*)qv, (float4*)out);
    }
}

// Round 11
// 140.182 us; speedup vs baseline: 1.1612x; 1.0085x over previous
//
#include <hip/hip_runtime.h>
#include <hip/hip_bf16.h>
#include <math.h>

typedef unsigned short u16;
typedef unsigned int   u32;
typedef __attribute__((ext_vector_type(8))) short  bf16x8;
typedef __attribute__((ext_vector_type(4))) float  floatx4;

#define NB 2
#define NT 4
#define CK 64
#define CV 256
#define HH 64
#define WW 64
#define MM 4096    // NT*32*32
#define NN 4096    // HH*WW
#define SCALE 0.125f
#define SHIFT 4.0f
#define OUT_B 2097152      // f32 elems per batch in out (512*4096)
#define NW 64              // n-columns per attn block
#define ITG 16             // iters per block (m-half: 16 x 128 = 2048)
// exp(x*SCALE - SHIFT) = exp2(x*C1 + C2)
#define C1 0.18033688011112042f
#define C2 (-5.770780163555853f)

__device__ __forceinline__ u16 f2b(float f) {
    __hip_bfloat16 h = __float2bfloat16(f);
    union { __hip_bfloat16 h; u16 u; } v; v.h = h; return v.u;
}

// raw transcendental: D = 2^S0 (1 instr vs ~6-instr ocml exp2f w/o fast-math)
__device__ __forceinline__ float fexp2(float x) {
    float r;
    asm("v_exp_f32 %0, %1" : "=v"(r) : "v"(x));
    return r;
}
// packed bf16 convert: lo16 = cvt(a), hi16 = cvt(b) (1 instr vs ~12)
__device__ __forceinline__ u32 cvtpk_bf16(float a, float b) {
    u32 r;
    asm("v_cvt_pk_bf16_f32 %0, %1, %2" : "=v"(r) : "v"(a), "v"(b));
    return r;
}

// ============================ fast (MFMA) path ============================
// prep: K -> pk2[b][cblk(8)][m(4096)][8c]  (fragment-tiled, 16B stores)
//       V -> vt[b][c][m]                    (8B ushort4 stores)
//       qv -> out[:, 0:256, :, :]           (float4 copy)
#define PRE_K 65536        // NB*8*4096
#define PRE_V 589824       // + NB*CV*MM/4 (=524288)
#define PRE_T 1114112      // + NB*CV*HH*WW/4 (=524288)

__global__ void prep(const float* __restrict__ mk, const float* __restrict__ mv,
                     const float4* __restrict__ qv,
                     u16* __restrict__ pk2, u16* __restrict__ vt,
                     float* __restrict__ out) {
    int u = blockIdx.x * 256 + threadIdx.x;
    if (u < PRE_K) {
        // one thread = 8 c-values at one m -> coalesced float2 reads, 16B write
        int m = u & 4095, cb8 = (u >> 12) & 7, b = u >> 15;
        int t = m >> 10, hh = (m >> 5) & 31, ww = m & 31;
        const float* s0 = mk + ((size_t)((b*NT + t)*CK + cb8*8))*(HH*WW)
                             + (2*hh)*WW + 2*ww;
        bf16x8 fr;
        #pragma unroll
        for (int i = 0; i < 8; ++i) {
            const float* s = s0 + (size_t)i*(HH*WW);
            float2 r0 = *(const float2*)s;
            float2 r1 = *(const float2*)(s + WW);
            fr[i] = (short)f2b(fmaxf(fmaxf(r0.x, r0.y), fmaxf(r1.x, r1.y)));
        }
        *(bf16x8*)(pk2 + ((size_t)(b*8 + cb8)*MM + m)*8) = fr;
    } else if (u < PRE_V) {
        // one thread = 4 consecutive m at one c -> float4 reads, 8B write
        int u2 = u - PRE_K;
        int m4 = u2 & 1023, c = (u2 >> 10) & 255, b = u2 >> 18;
        int t = m4 >> 8, hh = (m4 >> 3) & 31, w8 = m4 & 7;
        const float* s0 = mv + ((size_t)((b*NT + t)*CV + c))*(HH*WW)
                             + (2*hh)*WW + 8*w8;
        float4 a0 = *(const float4*)(s0);
        float4 a1 = *(const float4*)(s0 + 4);
        float4 b0 = *(const float4*)(s0 + WW);
        float4 b1 = *(const float4*)(s0 + WW + 4);
        ushort4 r;
        r.x = f2b(fmaxf(fmaxf(a0.x, a0.y), fmaxf(b0.x, b0.y)));
        r.y = f2b(fmaxf(fmaxf(a0.z, a0.w), fmaxf(b0.z, b0.w)));
        r.z = f2b(fmaxf(fmaxf(a1.x, a1.y), fmaxf(b1.x, b1.y)));
        r.w = f2b(fmaxf(fmaxf(a1.z, a1.w), fmaxf(b1.z, b1.w)));
        *(ushort4*)(vt + ((size_t)(b*CV + c)*MM) + m4*4) = r;
    } else {
        int u3 = u - PRE_V;
        int b = u3 >> 18, ru = u3 & 262143;
        ((float4*)out)[(size_t)b*(OUT_B/4) + ru] = qv[u3];
    }
}

// ---- attn phases ----
// QK: wave w owns m-rows [16w,16w+16) of the 128-m iter, all 64 n.
// S C-layout: n_l = t*16+lrow, m_l = 16w + quad*4 + r. VALU-thin epilogue.
__device__ __forceinline__ void qk_phase(bf16x8 k0, bf16x8 k1,
        const bf16x8 (&qf)[2][4], float (&sacc)[4],
        u16* __restrict__ Pd, int lrow, int cbw, int sw)
{
    #pragma unroll
    for (int t = 0; t < 4; ++t) {
        floatx4 s = __builtin_amdgcn_mfma_f32_16x16x32_bf16(
                        k0, qf[0][t], (floatx4){0.f,0.f,0.f,0.f}, 0, 0, 0);
        s = __builtin_amdgcn_mfma_f32_16x16x32_bf16(k1, qf[1][t], s, 0, 0, 0);
        float p0 = fexp2(__builtin_fmaf(s[0], C1, C2));
        float p1 = fexp2(__builtin_fmaf(s[1], C1, C2));
        float p2 = fexp2(__builtin_fmaf(s[2], C1, C2));
        float p3 = fexp2(__builtin_fmaf(s[3], C1, C2));
        sacc[t] += (p0 + p1) + (p2 + p3);
        u32 d0 = cvtpk_bf16(p0, p1);
        u32 d1 = cvtpk_bf16(p2, p3);
        *(uint2*)&Pd[(t*16 + lrow)*128 + ((cbw ^ sw) << 2)] = make_uint2(d0, d1);
    }
}

// PV full-CV: wave w owns c-rows [32w, 32w+32) (8 waves x 32 = 256 = all CV).
// Each pf (b128 read) feeds TWO MFMAs (c-tiles j=0,1): 16 reads -> 32 MFMAs,
// i.e. 0.5 LDS reads per MFMA (v9 was 1.0).
__device__ __forceinline__ void pv_phase(const bf16x8 (&vf)[4][2],
        floatx4 (&oacc)[2][4], const u16* __restrict__ Ps,
        int lrow, int quad, int sw)
{
    #pragma unroll
    for (int kt = 0; kt < 4; ++kt) {
        int cb = (kt << 3) + (quad << 1);
        #pragma unroll
        for (int nt = 0; nt < 4; ++nt) {
            bf16x8 pf = *(const bf16x8*)&Ps[(nt*16 + lrow)*128 + ((cb ^ sw) << 2)];
            __builtin_amdgcn_s_setprio(1);
            oacc[0][nt] = __builtin_amdgcn_mfma_f32_16x16x32_bf16(
                              vf[kt][0], pf, oacc[0][nt], 0, 0, 0);
            oacc[1][nt] = __builtin_amdgcn_mfma_f32_16x16x32_bf16(
                              vf[kt][1], pf, oacc[1][nt], 0, 0, 0);
            __builtin_amdgcn_s_setprio(0);
        }
    }
}

// Full-CV attention + m-split x2 (v8's proven part/sums epilogue machinery):
// grid 256 = 64nt x 2b x 2ms; 512 threads = 8 waves.
// vs v9: NO QK duplication (c-split removed -> QK MFMA+exp halved/CU) and
// each P LDS read feeds 2 MFMAs (LDS read traffic halved/CU). PV MFMA count
// and V L2 traffic unchanged. P dbuf, ONE barrier/iter, v9's VALU-thin QK.
__launch_bounds__(512, 2)
__global__ void attn_v10(const u16* __restrict__ pk2, const u16* __restrict__ vt,
                         const float* __restrict__ qk,
                         float* __restrict__ part, float* __restrict__ sums) {
    const int bid = blockIdx.x;
    const int xcd = bid & 7, grp = bid >> 3;        // presumed bid%8 -> XCD
    const int b   = (xcd >> 2) & 1;                 // (b,ms) K/V slice ~1.5MB: L2-fits
    const int ms  = xcd & 1;
    const int ntile = (((xcd >> 1) & 1) << 5) | grp; // 0..63
    const int tid = threadIdx.x, w = tid >> 6, l = tid & 63;
    const int lrow = l & 15, quad = l >> 4;
    const int n0 = ntile * NW;
    const int sw  = lrow << 1;                      // P XOR swizzle (keeps 16B pairs)
    const int cbw = (w << 2) + quad;                // QK write chunk = m_l>>2
    const int mstart = ms << 11;                    // 2048*ms

    __shared__ __align__(16) u16 P[2][NW * 128];    // 2 x 16 KB
    __shared__ float sums_s[8][NW];

    // Q B-fragments: B[k=c][n]: n = n0+t*16+lrow, c = cc*32+quad*8+i
    bf16x8 qf[2][4];
    const float* qb = qk + (size_t)b * CK * NN + n0;
    #pragma unroll
    for (int cc = 0; cc < 2; ++cc)
        #pragma unroll
        for (int t = 0; t < 4; ++t)
            #pragma unroll
            for (int i = 0; i < 8; ++i) {
                int c = cc*32 + quad*8 + i;
                qf[cc][t][i] = (short)f2b(qb[(size_t)c*NN + t*16 + lrow]);
            }

    const u16* pkb  = pk2 + (size_t)b * (8*MM*8);
    const int  mrw  = mstart + w*16 + lrow;         // K A-frag m-row (global)
    // V A-frag rows: c = 32w + j*16 + lrow, m = mstart + it*128 + kt*32 + quad*8
    const u16* vrow = vt + ((size_t)b*CV + w*32 + lrow)*MM + mstart + quad*8;

    floatx4 oacc[2][4];
    #pragma unroll
    for (int j = 0; j < 2; ++j)
        #pragma unroll
        for (int nt = 0; nt < 4; ++nt)
            oacc[j][nt] = (floatx4){0.f, 0.f, 0.f, 0.f};
    float sacc[4] = {0.f, 0.f, 0.f, 0.f};

    // ---- preamble: loads for local iter 0, QK(0) -> P[0]
    bf16x8 k0 = *(const bf16x8*)(pkb + ((size_t)quad*MM + mrw)*8);
    bf16x8 k1 = *(const bf16x8*)(pkb + ((size_t)(quad+4)*MM + mrw)*8);
    bf16x8 vf[4][2];
    #pragma unroll
    for (int kt = 0; kt < 4; ++kt)
        #pragma unroll
        for (int j = 0; j < 2; ++j)
            vf[kt][j] = *(const bf16x8*)(vrow + (size_t)j*(16*MM) + kt*32);
    qk_phase(k0, k1, qf, sacc, P[0], lrow, cbw, sw);

    for (int it = 0; it < ITG - 1; ++it) {
        __syncthreads();                            // P[it&1] complete
        const int mb2 = (it + 1) << 7;              // local m-offset of it+1
        bf16x8 k0n = *(const bf16x8*)(pkb + ((size_t)quad*MM + mb2 + mrw)*8);
        bf16x8 k1n = *(const bf16x8*)(pkb + ((size_t)(quad+4)*MM + mb2 + mrw)*8);
        bf16x8 vn[4][2];
        #pragma unroll
        for (int kt = 0; kt < 4; ++kt)
            #pragma unroll
            for (int j = 0; j < 2; ++j)
                vn[kt][j] = *(const bf16x8*)(vrow + (size_t)j*(16*MM) + mb2 + kt*32);
        pv_phase(vf, oacc, P[it & 1], lrow, quad, sw);
        qk_phase(k0n, k1n, qf, sacc, P[(it + 1) & 1], lrow, cbw, sw);
        #pragma unroll
        for (int kt = 0; kt < 4; ++kt)
            #pragma unroll
            for (int j = 0; j < 2; ++j)
                vf[kt][j] = vn[kt][j];
    }
    __syncthreads();
    pv_phase(vf, oacc, P[(ITG - 1) & 1], lrow, quad, sw);

    // ---- partial softmax denominator: quad-reduce, then 8-wave LDS reduce
    #pragma unroll
    for (int t = 0; t < 4; ++t) {
        float v = sacc[t];
        v += __shfl_xor(v, 16, 64);
        v += __shfl_xor(v, 32, 64);
        if (l < 16) sums_s[w][t*16 + l] = v;
    }
    __syncthreads();

    // ---- write partial O tile [256c][64n]
    float* pb = part + ((size_t)((ms*NB + b)*64 + ntile)) * (256*64);
    #pragma unroll
    for (int j = 0; j < 2; ++j)
        #pragma unroll
        for (int nt = 0; nt < 4; ++nt)
            #pragma unroll
            for (int r = 0; r < 4; ++r) {
                int c_loc = w*32 + j*16 + quad*4 + r;
                pb[c_loc*64 + nt*16 + lrow] = oacc[j][nt][r];
            }
    if (tid < 64) {
        float sv = 0.f;
        #pragma unroll
        for (int w2 = 0; w2 < 8; ++w2) sv += sums_s[w2][tid];
        sums[((size_t)((ms*NB + b)*64 + ntile))*64 + tid] = sv;
    }
}

// combine m-split partials + normalize: O = (part0+part1)/(d0+d1)
__global__ void epilogue3(const float* __restrict__ part,
                          const float* __restrict__ sums,
                          float* __restrict__ out) {
    int e = blockIdx.x * 256 + threadIdx.x;        // 524288 = 2b*256c*64nt*16n4
    int nl4 = e & 15;
    int nt  = (e >> 4) & 63;
    int c   = (e >> 10) & 255;
    int b   = e >> 18;
    const float4* p4 = (const float4*)part;
    const float4* s4 = (const float4*)sums;
    size_t t0 = (size_t)((0*NB + b)*64 + nt);
    size_t t1 = (size_t)((1*NB + b)*64 + nt);
    float4 u0 = p4[t0*4096 + c*16 + nl4];          // 256c*64n/4 = 4096 f4/tile
    float4 u1 = p4[t1*4096 + c*16 + nl4];
    float4 d0 = s4[t0*16 + nl4];
    float4 d1 = s4[t1*16 + nl4];
    float4 r;
    r.x = (u0.x + u1.x) / (d0.x + d1.x);
    r.y = (u0.y + u1.y) / (d0.y + d1.y);
    r.z = (u0.z + u1.z) / (d0.z + d1.z);
    r.w = (u0.w + u1.w) / (d0.w + d1.w);
    ((float4*)out)[(size_t)(b*512 + 256 + c)*1024 + nt*16 + nl4] = r;
}

// ======================= fallback (proven round-4) path =======================

__global__ void pool_v_f32(const float* __restrict__ src, float* __restrict__ out) {
    int e = blockIdx.x * 256 + threadIdx.x;
    int c = e & 255;
    int r = e >> 8;
    int ww = r & 31;  int hh = (r >> 5) & 31;
    int t  = (r >> 10) & 3;  int b = r >> 12;
    int m  = r & (MM - 1);
    const float* s = src + ((size_t)(((b*NT + t)*CV + c)*HH + 2*hh))*WW + 2*ww;
    out[(size_t)b*OUT_B + (size_t)m*CV + c] = fmaxf(fmaxf(s[0], s[1]), fmaxf(s[WW], s[WW+1]));
}

__global__ void pool_k_f32(const float* __restrict__ src, float* __restrict__ dst) {
    int e = blockIdx.x * 256 + threadIdx.x;
    int c = e & 63;
    int r = e >> 6;
    int ww = r & 31;  int hh = (r >> 5) & 31;
    int t  = (r >> 10) & 3;  int b = r >> 12;
    const float* s = src + ((size_t)(((b*NT + t)*CK + c)*HH + 2*hh))*WW + 2*ww;
    dst[e] = fmaxf(fmaxf(s[0], s[1]), fmaxf(s[WW], s[WW+1]));
}

__global__ void copy_qv_f32(const float4* __restrict__ src, float4* __restrict__ dst) {
    int u = blockIdx.x * 256 + threadIdx.x;
    int b  = u >> 18;
    int ru = u & 262143;
    dst[(size_t)b * (OUT_B/4) + ru] = src[u];
}

template<bool STAGED_K>
__launch_bounds__(256)
__global__ void attn_old(const float* __restrict__ pk,
                         const float* __restrict__ mk,
                         const float* __restrict__ qk,
                         float* __restrict__ out) {
    __shared__ __align__(16) float q_lds[CK][4];
    __shared__ __align__(16) float sarr[4][MM];
    __shared__ float inv_l[4];

    const int tid = threadIdx.x;
    const int blk = blockIdx.x;
    const int b   = blk >> 10;
    const int n0  = (blk & 1023) << 2;

    {
        int c = tid >> 2, qi = tid & 3;
        q_lds[c][qi] = qk[((size_t)(b*CK + c))*NN + n0 + qi];
    }
    __syncthreads();

    #pragma unroll
    for (int i = 0; i < 16; ++i) {
        int m = tid + (i << 8);
        float a0 = 0.f, a1 = 0.f, a2 = 0.f, a3 = 0.f;
        if (STAGED_K) {
            const float4* k4 = reinterpret_cast<const float4*>(pk + ((size_t)b*MM + m)*CK);
            #pragma unroll
            for (int cc = 0; cc < 16; ++cc) {
                float4 kv = k4[cc];
                int c = cc*4;
                float4 q0 = *reinterpret_cast<const float4*>(&q_lds[c][0]);
                float4 q1 = *reinterpret_cast<const float4*>(&q_lds[c+1][0]);
                float4 q2 = *reinterpret_cast<const float4*>(&q_lds[c+2][0]);
                float4 q3 = *reinterpret_cast<const float4*>(&q_lds[c+3][0]);
                a0 += kv.x*q0.x + kv.y*q1.x + kv.z*q2.x + kv.w*q3.x;
                a1 += kv.x*q0.y + kv.y*q1.y + kv.z*q2.y + kv.w*q3.y;
                a2 += kv.x*q0.z + kv.y*q1.z + kv.z*q2.z + kv.w*q3.z;
                a3 += kv.x*q0.w + kv.y*q1.w + kv.z*q2.w + kv.w*q3.w;
            }
        } else {
            int ww = m & 31, hh = (m >> 5) & 31, t = m >> 10;
            const float* base = mk + ((size_t)((b*NT + t)*CK)*HH + 2*hh)*WW + 2*ww;
            for (int c = 0; c < CK; ++c) {
                const float* s = base + (size_t)c*HH*WW;
                float kv = fmaxf(fmaxf(s[0], s[1]), fmaxf(s[WW], s[WW+1]));
                float4 q = *reinterpret_cast<const float4*>(&q_lds[c][0]);
                a0 += kv*q.x; a1 += kv*q.y; a2 += kv*q.z; a3 += kv*q.w;
            }
        }
        sarr[0][m] = a0*SCALE;
        sarr[1][m] = a1*SCALE;
        sarr[2][m] = a2*SCALE;
        sarr[3][m] = a3*SCALE;
    }
    __syncthreads();

    const int wave = tid >> 6, lane = tid & 63;
    float mx = -3.0e38f;
    for (int m = lane; m < MM; m += 64) mx = fmaxf(mx, sarr[wave][m]);
    #pragma unroll
    for (int off = 32; off > 0; off >>= 1) mx = fmaxf(mx, __shfl_xor(mx, off, 64));
    float ls = 0.f;
    for (int m = lane; m < MM; m += 64) {
        float p = __expf(sarr[wave][m] - mx);
        sarr[wave][m] = p;
        ls += p;
    }
    #pragma unroll
    for (int off = 32; off > 0; off >>= 1) ls += __shfl_xor(ls, off, 64);
    if (lane == 0) inv_l[wave] = 1.0f / ls;
    __syncthreads();

    const int c4 = lane;
    const float4* vb = reinterpret_cast<const float4*>(out + (size_t)b*OUT_B) + c4;
    const float* prow = sarr[wave];
    float a0 = 0.f, a1 = 0.f, a2 = 0.f, a3 = 0.f;
    for (int m = 0; m < MM; m += 4) {
        float4 p4 = *reinterpret_cast<const float4*>(prow + m);
        const float4* vp = vb + (size_t)m*(CV/4);
        float4 v0 = vp[0], v1 = vp[CV/4], v2 = vp[CV/2], v3 = vp[3*(CV/4)];
        a0 += p4.x*v0.x + p4.y*v1.x + p4.z*v2.x + p4.w*v3.x;
        a1 += p4.x*v0.y + p4.y*v1.y + p4.z*v2.y + p4.w*v3.y;
        a2 += p4.x*v0.z + p4.y*v1.z + p4.z*v2.z + p4.w*v3.z;
        a3 += p4.x*v0.w + p4.y*v1.w + p4.z*v2.w + p4.w*v3.w;
    }

    float inv = inv_l[wave];
    int n = n0 + wave;
    size_t ob = ((size_t)(b*512 + 256 + c4*4))*NN + n;
    out[ob]        = a0*inv;
    out[ob + NN]   = a1*inv;
    out[ob + 2*NN] = a2*inv;
    out[ob + 3*NN] = a3*inv;
}

// ================================ launcher ================================

extern "C" void kernel_launch(void* const* d_in, const int* in_sizes, int n_in,
                              void* d_out, int out_size, void* d_ws, size_t ws_size,
                              hipStream_t stream) {
    const float* mk = (const float*)d_in[0];
    const float* mv = (const float*)d_in[1];
    const float* qk = (const float*)d_in[2];
    const float* qv = (const float*)d_in[3];
    float* out = (float*)d_out;

    // fast-path ws layout: pk2 1MB | vt 4MB | part 16MB | sums 64KB (~21.9MB)
    u16* pk2 = (u16*)d_ws;
    u16* vt  = pk2 + (size_t)NB*8*MM*8;                 // 524288 u16
    float* part = (float*)(vt + (size_t)NB*CV*MM);      // 4194304 f32
    float* sums = part + 4194304;                       // 16384 f32
    const size_t need = ((size_t)NB*8*MM*8 + (size_t)NB*CV*MM) * sizeof(u16)
                      + (4194304 + 16384) * sizeof(float);

    if (ws_size >= need) {
        prep<<<PRE_T/256, 256, 0, stream>>>(mk, mv, (const float4*)qv, pk2, vt, out);
        attn_v10<<<256, 512, 0, stream>>>(pk2, vt, qk, part, sums);
        epilogue3<<<524288/256, 256, 0, stream>>>(part, sums, out);
    } else {
        const size_t pk_bytes = (size_t)NB*MM*CK*sizeof(float);
        const bool staged = (ws_size >= pk_bytes);
        float* pk = (float*)d_ws;
        pool_v_f32<<<(NB*MM*CV)/256, 256, 0, stream>>>(mv, out);
        if (staged) {
            pool_k_f32<<<(NB*MM*CK)/256, 256, 0, stream>>>(mk, pk);
            attn_old<true ><<<NB*(NN/4), 256, 0, stream>>>(pk, mk, qk, out);
        } else {
            attn_old<false><<<NB*(NN/4), 256, 0, stream>>>(pk, mk, qk, out);
        }
        copy_qv_f32<<<((NB*CV*HH*WW)/4)/256, 256, 0, stream>>>((const float4*)qv, (float4*)out);
    }
}